// Round 1
// baseline (440.424 us; speedup 1.0000x reference)
//
#include <hip/hip_runtime.h>

// Problem: x (128,128,56,56) f32, w (32,128,3) f32.
// out[n,o,(h+1)%56,w] = sum_c sum_k x[n,c,h,w+k-1] * w[o,c,k]  (pad W by 1)
// Flatten s = h*56+w; rows independent via masks at w==0 / w==55.

#define NB   128
#define CIN  128
#define SP   3136          // 56*56
#define OUTC 32
#define ST   64            // s-tile per block (3136 = 49*64)
#define PITCH 68           // LDS row pitch in floats (66 used, pad to 68)

// Reorder w[o][c][k] (o*384 + c*3 + k) -> wr[og][c][oo][k] = og*3072 + c*24 + oo*3 + k
__global__ void reorder_w_kernel(const float* __restrict__ w, float* __restrict__ wr) {
    int i = blockIdx.x * 256 + threadIdx.x;
    if (i >= OUTC * CIN * 3) return;
    int k = i % 3;
    int r = i / 3;
    int c = r % CIN;
    int o = r / CIN;
    int og = o >> 3, oo = o & 7;
    wr[og * (CIN * 24) + c * 24 + oo * 3 + k] = w[o * (CIN * 3) + c * 3 + k];
}

__launch_bounds__(256, 4)
__global__ void conv_roll_kernel(const float* __restrict__ x,
                                 const float* __restrict__ wr,
                                 float* __restrict__ out) {
    __shared__ float xs[CIN * PITCH];   // 34816 B

    const int n  = blockIdx.y;
    const int s0 = blockIdx.x * ST;

    // ---- stage x[n, :, s0-1 .. s0+64] into LDS (66 floats per c) ----
    const long nbase = (long)n * (CIN * SP);
    const long lim   = (long)NB * CIN * SP - 1;
    for (int idx = threadIdx.x; idx < CIN * 66; idx += 256) {
        int c = idx / 66;
        int j = idx - c * 66;
        long g = nbase + (long)c * SP + (s0 - 1 + j);
        g = g < 0 ? 0 : (g > lim ? lim : g);   // only clips the 2 global-extreme blocks; values masked at use
        xs[c * PITCH + j] = x[g];
    }
    __syncthreads();

    const int sl = threadIdx.x & 63;
    const int og = __builtin_amdgcn_readfirstlane(threadIdx.x >> 6);  // wave-uniform o-group
    const int s  = s0 + sl;
    const int w  = s % 56;
    const float m0 = (w == 0)  ? 0.0f : 1.0f;
    const float m2 = (w == 55) ? 0.0f : 1.0f;

    const float* __restrict__ wp = wr + og * (CIN * 24);

    float acc[8];
#pragma unroll
    for (int oo = 0; oo < 8; ++oo) acc[oo] = 0.0f;

#pragma unroll 4
    for (int c = 0; c < CIN; ++c) {
        const float x0 = xs[c * PITCH + sl]     * m0;
        const float x1 = xs[c * PITCH + sl + 1];
        const float x2 = xs[c * PITCH + sl + 2] * m2;
        const float* __restrict__ wc = wp + c * 24;   // 24 contiguous floats -> s_load_dwordx8 x3
#pragma unroll
        for (int oo = 0; oo < 8; ++oo) {
            acc[oo] += wc[oo * 3 + 0] * x0 + wc[oo * 3 + 1] * x1 + wc[oo * 3 + 2] * x2;
        }
    }

    // ---- store with roll: y[s] -> out[(s+56) mod 3136] ----
    int sst = s + 56;
    if (sst >= SP) sst -= SP;
    float* op = out + (long)n * (OUTC * SP) + (long)(og * 8) * SP + sst;
#pragma unroll
    for (int oo = 0; oo < 8; ++oo) op[(long)oo * SP] = acc[oo];
}

extern "C" void kernel_launch(void* const* d_in, const int* in_sizes, int n_in,
                              void* d_out, int out_size, void* d_ws, size_t ws_size,
                              hipStream_t stream) {
    const float* x = (const float*)d_in[0];
    const float* w = (const float*)d_in[1];
    float* out = (float*)d_out;
    float* wr  = (float*)d_ws;   // 12288 floats = 48 KB

    reorder_w_kernel<<<dim3((OUTC * CIN * 3 + 255) / 256), dim3(256), 0, stream>>>(w, wr);

    dim3 grid(SP / ST, NB);      // 49 x 128
    conv_roll_kernel<<<grid, dim3(256), 0, stream>>>(x, wr, out);
}

// Round 2
// 359.430 us; speedup vs baseline: 1.2253x; 1.2253x over previous
//
#include <hip/hip_runtime.h>

// out[n,o,(h+1)%56,w] = sum_{c,t} x[n,c,h,w+t-1] * W[o,c,t]   (W-pad 1, H-pad 0)
// Implicit GEMM on MFMA: C[o=32][s] = sum_{k=tap*128+c} A[o][k] * B[k][s],
// B[k][s] = x[n][c][s+tap-1] (masked at row boundaries). bf16 hi/lo split x3
// MFMAs for ~fp32 accuracy. Memory floor ~41us (256MB @ 6.3TB/s).

#define NB    128
#define CIN   128
#define SP    3136          // 56*56
#define OUTC  32
#define ST    96            // s-cols per block (3 waves x 32)
#define NT    33            // ceil(3136/96); last tile 64 valid cols
#define ROWS  98            // ST+2 window rows (j=0 <-> s0-1)
#define CP    136           // LDS row pitch in bf16: 272B, 16B-aligned rows for ds_read_b128
#define THREADS 192

typedef __attribute__((ext_vector_type(8)))  short bf16x8;   // 8 bf16 = 4 VGPRs
typedef __attribute__((ext_vector_type(16))) float f32x16;   // 32x32 accumulator

__device__ __forceinline__ unsigned short f2bf(float f) {    // RNE f32->bf16
    unsigned u = __float_as_uint(f);
    return (unsigned short)((u + 0x7FFFu + ((u >> 16) & 1u)) >> 16);
}
__device__ __forceinline__ float bf2f(unsigned short h) {
    return __uint_as_float(((unsigned)h) << 16);
}

// A-fragment prep: af[kstep][plane(hi/lo)][lane][8] bf16, frag = A[m=lane&31][k=kstep*16+(lane>>5)*8+j]
// K ordering: k = tap*128 + c  (so each 16-wide k-step stays within one tap)
__global__ void prep_w(const float* __restrict__ w, unsigned short* __restrict__ af) {
    int i = blockIdx.x * 256 + threadIdx.x;            // over 32 o x 384 k
    if (i >= OUTC * 384) return;
    int k = i % 384, o = i / 384;
    int tap = k / 128, c = k % 128;
    float v = w[o * 384 + c * 3 + tap];
    unsigned short hi = f2bf(v);
    unsigned short lo = f2bf(v - bf2f(hi));
    int kstep = k >> 4, klocal = k & 15;
    int lane  = ((klocal >> 3) << 5) + o;              // (lane>>5)*8 + j = klocal
    int j     = klocal & 7;
    af[(kstep * 2 + 0) * 512 + lane * 8 + j] = hi;
    af[(kstep * 2 + 1) * 512 + lane * 8 + j] = lo;
}

__launch_bounds__(THREADS, 2)
__global__ void conv_mfma(const float* __restrict__ x,
                          const unsigned short* __restrict__ af,
                          float* __restrict__ out) {
    __shared__ unsigned short xs_hi[ROWS * CP];        // 26656 B
    __shared__ unsigned short xs_lo[ROWS * CP];        // total 53312 B -> 3 blocks/CU

    const int n  = blockIdx.y;
    const int s0 = blockIdx.x * ST;
    const float* __restrict__ xn = x + (size_t)n * (CIN * SP);

    // ---- stage x[n, :, s0-1 .. s0+ST] transposed into LDS as bf16 hi/lo ----
    // item i: j = i % ROWS (lane-consecutive -> coalesced global), cpair = i / ROWS
    for (int i = threadIdx.x; i < (CIN / 2) * ROWS; i += THREADS) {
        int j  = i % ROWS;
        int cp = i / ROWS;
        int sp = s0 - 1 + j;
        sp = sp < 0 ? 0 : (sp > SP - 1 ? SP - 1 : sp);  // clamped; boundary values masked at use
        float v0 = xn[(2 * cp)     * SP + sp];
        float v1 = xn[(2 * cp + 1) * SP + sp];
        unsigned short h0 = f2bf(v0), h1 = f2bf(v1);
        unsigned short l0 = f2bf(v0 - bf2f(h0)), l1 = f2bf(v1 - bf2f(h1));
        *(unsigned*)&xs_hi[j * CP + 2 * cp] = (unsigned)h0 | ((unsigned)h1 << 16);
        *(unsigned*)&xs_lo[j * CP + 2 * cp] = (unsigned)l0 | ((unsigned)l1 << 16);
    }
    __syncthreads();

    const int lane = threadIdx.x & 63;
    const int wid  = threadIdx.x >> 6;                 // wave -> 32-col chunk
    const int col  = s0 + wid * 32 + (lane & 31);      // global s for this lane's column
    const int wpos = col % 56;
    const bool mL = (wpos != 0);                       // tap0 valid
    const bool mR = (wpos != 55);                      // tap2 valid
    const int half = lane >> 5;                        // k-half within frag
    const int jbase = wid * 32 + (lane & 31);          // window row for tap=1 is jbase+1

    f32x16 acc;
#pragma unroll
    for (int r = 0; r < 16; ++r) acc[r] = 0.0f;

#pragma unroll
    for (int tap = 0; tap < 3; ++tap) {
        const int jrow = jbase + tap;
        const unsigned short* ph = &xs_hi[jrow * CP + half * 8];
        const unsigned short* pl = &xs_lo[jrow * CP + half * 8];
        const bool kill = (tap == 0 && !mL) || (tap == 2 && !mR);
#pragma unroll
        for (int ks8 = 0; ks8 < 8; ++ks8) {
            const int ks = tap * 8 + ks8;
            bf16x8 bhi = *(const bf16x8*)(ph + ks8 * 16);
            bf16x8 blo = *(const bf16x8*)(pl + ks8 * 16);
            if (kill) {
#pragma unroll
                for (int t = 0; t < 8; ++t) { bhi[t] = 0; blo[t] = 0; }
            }
            const bf16x8 ahi = *(const bf16x8*)(af + (ks * 2 + 0) * 512 + lane * 8);
            const bf16x8 alo = *(const bf16x8*)(af + (ks * 2 + 1) * 512 + lane * 8);
            acc = __builtin_amdgcn_mfma_f32_32x32x16_bf16(ahi, bhi, acc, 0, 0, 0);
            acc = __builtin_amdgcn_mfma_f32_32x32x16_bf16(ahi, blo, acc, 0, 0, 0);
            acc = __builtin_amdgcn_mfma_f32_32x32x16_bf16(alo, bhi, acc, 0, 0, 0);
        }
    }

    // ---- store with roll: col s -> (s+56) mod 3136 ; C/D: col=lane&31, row=(r&3)+8*(r>>2)+4*(lane>>5)
    if (col < SP) {
        int sst = col + 56;
        if (sst >= SP) sst -= SP;
        float* op = out + (size_t)n * (OUTC * SP) + sst;
#pragma unroll
        for (int r = 0; r < 16; ++r) {
            int o = (r & 3) + 8 * (r >> 2) + 4 * half;
            op[o * SP] = acc[r];
        }
    }
}

extern "C" void kernel_launch(void* const* d_in, const int* in_sizes, int n_in,
                              void* d_out, int out_size, void* d_ws, size_t ws_size,
                              hipStream_t stream) {
    const float* x = (const float*)d_in[0];
    const float* w = (const float*)d_in[1];
    float* out = (float*)d_out;
    unsigned short* af = (unsigned short*)d_ws;        // 24*2*512 bf16 = 48 KB

    prep_w<<<dim3((OUTC * 384 + 255) / 256), dim3(256), 0, stream>>>(w, af);

    dim3 grid(NT, NB);                                  // 33 x 128
    conv_mfma<<<grid, dim3(THREADS), 0, stream>>>(x, af, out);
}

// Round 4
// 311.889 us; speedup vs baseline: 1.4121x; 1.1524x over previous
//
#include <hip/hip_runtime.h>

// out[n,o,(h+1)%56,w] = sum_{c,t} x[n,c,h,w+t-1] * W[o,c,t]   (W-pad 1, H-pad 0)
// Implicit GEMM on MFMA 32x32x16_bf16, plain bf16 (err ~0.3 << 2.24 threshold).
// K = tap*128 + c. B[k][s] = x[n][c][s+tap-1], masked at w-row boundaries.
// LDS: x-window transposed, rows j (=s offset) of 128 c in bf16, pitch 68 dwords
// -> both b128 reads (granule (17j+g)%8) and b128 writes are bank-conflict-free.

#define NB    128
#define CIN   128
#define SP    3136          // 56*56
#define OUTC  32
#define ST    128           // s-cols per block (4 waves x 32)
#define NT    25            // ceil(3136/128)
#define ROWS  130           // ST+2 window rows (j=0 <-> s0-1)
#define CP    136           // LDS row pitch in bf16 (68 dwords; 17%8=1 -> conflict-free b128)
#define THREADS 256

typedef __attribute__((ext_vector_type(8)))  short bf16x8;   // 8 bf16 = 4 VGPRs
typedef __attribute__((ext_vector_type(16))) float f32x16;   // 32x32 accumulator

__device__ __forceinline__ unsigned short f2bf(float f) {    // RNE f32->bf16
    unsigned u = __float_as_uint(f);
    return (unsigned short)((u + 0x7FFFu + ((u >> 16) & 1u)) >> 16);
}
__device__ __forceinline__ unsigned pack2bf(float a, float b) {
    return (unsigned)f2bf(a) | ((unsigned)f2bf(b) << 16);
}

// A-frag prep: af[ks][lane][8] bf16; frag element j of lane = A[m=lane&31][k=ks*16+(lane>>5)*8+j]
// k = tap*128 + c
__global__ void prep_w(const float* __restrict__ w, unsigned short* __restrict__ af) {
    int i = blockIdx.x * 256 + threadIdx.x;            // over 32 o x 384 k
    if (i >= OUTC * 384) return;
    int k = i % 384, o = i / 384;
    int tap = k / 128, c = k % 128;
    int kstep = k >> 4, klocal = k & 15;
    int lane  = ((klocal >> 3) << 5) + o;
    int j     = klocal & 7;
    af[kstep * 512 + lane * 8 + j] = f2bf(w[o * 384 + c * 3 + tap]);
}

__launch_bounds__(THREADS, 4)
__global__ void conv_mfma(const float* __restrict__ x,
                          const unsigned short* __restrict__ af,
                          float* __restrict__ out) {
    __shared__ unsigned short xs[ROWS * CP];           // 35,360 B -> 4 blocks/CU

    const int n  = blockIdx.y;
    const int s0 = blockIdx.x * ST;
    const float* __restrict__ xn = x + (size_t)n * (CIN * SP);

    // ---- stage x[n, :, s0-1 .. s0+ST] transposed into LDS as bf16 ----
    // item: one row j, one c-group of 8 -> 8 coalesced dword loads, 1 ds_write_b128
    for (int i = threadIdx.x; i < 16 * ROWS; i += THREADS) {   // 2080 items
        int j  = i % ROWS;                              // lane-consecutive -> coalesced sp
        int cg = i / ROWS;
        int sp = s0 - 1 + j;
        sp = sp < 0 ? 0 : (sp > SP - 1 ? SP - 1 : sp);  // clamped; boundary rows masked at use
        const float* __restrict__ xp = xn + (size_t)(cg * 8) * SP + sp;
        float v0 = xp[0 * SP], v1 = xp[1 * SP], v2 = xp[2 * SP], v3 = xp[3 * SP];
        float v4 = xp[4 * SP], v5 = xp[5 * SP], v6 = xp[6 * SP], v7 = xp[7 * SP];
        union { unsigned u[4]; bf16x8 v; } pk;
        pk.u[0] = pack2bf(v0, v1);
        pk.u[1] = pack2bf(v2, v3);
        pk.u[2] = pack2bf(v4, v5);
        pk.u[3] = pack2bf(v6, v7);
        *(bf16x8*)&xs[j * CP + cg * 8] = pk.v;
    }
    __syncthreads();

    const int lane  = threadIdx.x & 63;
    const int wid   = threadIdx.x >> 6;                // wave -> 32-col chunk
    const int cloc  = wid * 32 + (lane & 31);          // local column
    const int col   = s0 + cloc;                       // global s
    const int wpos  = col % 56;
    const int half  = lane >> 5;

    f32x16 acc;
#pragma unroll
    for (int r = 0; r < 16; ++r) acc[r] = 0.0f;

#pragma unroll
    for (int tap = 0; tap < 3; ++tap) {
        const unsigned short* brow = &xs[(cloc + tap) * CP + half * 8];
        const bool kill = (tap == 0 && wpos == 0) || (tap == 2 && wpos == 55);
#pragma unroll
        for (int ks8 = 0; ks8 < 8; ++ks8) {
            bf16x8 b = *(const bf16x8*)(brow + ks8 * 16);
            if (kill) {
#pragma unroll
                for (int t = 0; t < 8; ++t) b[t] = 0;
            }
            const bf16x8 a = *(const bf16x8*)(af + (tap * 8 + ks8) * 512 + lane * 8);
            acc = __builtin_amdgcn_mfma_f32_32x32x16_bf16(a, b, acc, 0, 0, 0);
        }
    }

    // ---- store with roll: s -> (s+56) mod 3136 ; C/D: col=lane&31, row=(r&3)+8*(r>>2)+4*half
    if (col < SP) {
        int sst = col + 56;
        if (sst >= SP) sst -= SP;
        float* op = out + (size_t)n * (OUTC * SP) + sst;
#pragma unroll
        for (int r = 0; r < 16; ++r) {
            int o = (r & 3) + 8 * (r >> 2) + 4 * half;
            op[o * SP] = acc[r];
        }
    }
}

extern "C" void kernel_launch(void* const* d_in, const int* in_sizes, int n_in,
                              void* d_out, int out_size, void* d_ws, size_t ws_size,
                              hipStream_t stream) {
    const float* x = (const float*)d_in[0];
    const float* w = (const float*)d_in[1];
    float* out = (float*)d_out;
    unsigned short* af = (unsigned short*)d_ws;        // 24*512 bf16 = 24 KB

    prep_w<<<dim3((OUTC * 384 + 255) / 256), dim3(256), 0, stream>>>(w, af);

    dim3 grid(NT, NB);                                  // 25 x 128
    conv_mfma<<<grid, dim3(THREADS), 0, stream>>>(x, af, out);
}

// Round 5
// 307.014 us; speedup vs baseline: 1.4345x; 1.0159x over previous
//
#include <hip/hip_runtime.h>

// out[n,o,(h+1)%56,w] = sum_{c,t} x[n,c,h,w+t-1] * W[o,c,t]   (W-pad 1, H-pad 0)
// Implicit GEMM on MFMA 32x32x16_bf16, plain bf16 (err ~0.3 << 2.24 threshold).
// K = tap*128 + c. B[k][s] = x[n][c][s+tap-1], masked at w-row boundaries.
// LDS: x-window transposed, ROWS=128 rows j of 128 c bf16, pitch 68 dwords ->
// reads & writes uniformly hit all 32 banks (conflict-free).
// ST=126 so staging = 2048 items = exactly 8/thread, fully unrolled & pipelined.

#define NB    128
#define CIN   128
#define SP    3136          // 56*56
#define OUTC  32
#define ST    126           // s-cols per block (cols 126,127 computed-garbage, masked at store)
#define NT    25            // ceil(3136/126)
#define ROWS  128           // window rows j=0 <-> s0-1
#define CP    136           // LDS row pitch in bf16 (68 dwords)
#define THREADS 256

typedef __attribute__((ext_vector_type(8)))  short bf16x8;   // 8 bf16 = 4 VGPRs
typedef __attribute__((ext_vector_type(16))) float f32x16;   // 32x32 accumulator

__device__ __forceinline__ unsigned short f2bf(float f) {    // RNE f32->bf16
    unsigned u = __float_as_uint(f);
    return (unsigned short)((u + 0x7FFFu + ((u >> 16) & 1u)) >> 16);
}
__device__ __forceinline__ unsigned pack2bf(float a, float b) {
    return (unsigned)f2bf(a) | ((unsigned)f2bf(b) << 16);
}

// A-frag prep: af[ks][lane][8] bf16; frag element j of lane = A[m=lane&31][k=ks*16+(lane>>5)*8+j]
// k = tap*128 + c
__global__ void prep_w(const float* __restrict__ w, unsigned short* __restrict__ af) {
    int i = blockIdx.x * 256 + threadIdx.x;            // over 32 o x 384 k
    if (i >= OUTC * 384) return;
    int k = i % 384, o = i / 384;
    int tap = k / 128, c = k % 128;
    int kstep = k >> 4, klocal = k & 15;
    int lane  = ((klocal >> 3) << 5) + o;
    int j     = klocal & 7;
    af[kstep * 512 + lane * 8 + j] = f2bf(w[o * 384 + c * 3 + tap]);
}

__launch_bounds__(THREADS, 4)
__global__ void conv_mfma(const float* __restrict__ x,
                          const unsigned short* __restrict__ af,
                          float* __restrict__ out) {
    __shared__ unsigned short xs[ROWS * CP];           // 34,816 B -> 4 blocks/CU

    const int n  = blockIdx.y;
    const int s0 = blockIdx.x * ST;
    const float* __restrict__ xn = x + (size_t)n * (CIN * SP);

    // ---- stage x[n, :, s0-1 .. s0+126] transposed into LDS as bf16 ----
    // 2048 items = 8/thread, static: j = i&127 (lane-consecutive -> coalesced), cg = i>>7
#pragma unroll
    for (int it = 0; it < 8; ++it) {
        int i  = threadIdx.x + it * THREADS;
        int j  = i & (ROWS - 1);
        int cg = i >> 7;
        int sp = s0 - 1 + j;
        sp = sp < 0 ? 0 : (sp > SP - 1 ? SP - 1 : sp);  // clamped; boundary rows masked at use
        const float* __restrict__ xp = xn + (size_t)(cg * 8) * SP + sp;
        float v0 = xp[0 * SP], v1 = xp[1 * SP], v2 = xp[2 * SP], v3 = xp[3 * SP];
        float v4 = xp[4 * SP], v5 = xp[5 * SP], v6 = xp[6 * SP], v7 = xp[7 * SP];
        union { unsigned u[4]; bf16x8 v; } pk;
        pk.u[0] = pack2bf(v0, v1);
        pk.u[1] = pack2bf(v2, v3);
        pk.u[2] = pack2bf(v4, v5);
        pk.u[3] = pack2bf(v6, v7);
        *(bf16x8*)&xs[j * CP + cg * 8] = pk.v;
    }
    __syncthreads();

    const int lane  = threadIdx.x & 63;
    const int wid   = threadIdx.x >> 6;                // wave -> 32-col chunk
    const int cloc  = wid * 32 + (lane & 31);          // local column (0..127; 126,127 garbage)
    const int col   = s0 + cloc;                       // global s
    const int wpos  = col % 56;
    const int half  = lane >> 5;

    f32x16 acc;
#pragma unroll
    for (int r = 0; r < 16; ++r) acc[r] = 0.0f;

#pragma unroll
    for (int tap = 0; tap < 3; ++tap) {
        int jrow = cloc + tap;
        if (jrow > ROWS - 1) jrow = ROWS - 1;          // only garbage cols 126,127
        const unsigned short* brow = &xs[jrow * CP + half * 8];
        const bool kill = (tap == 0 && wpos == 0) || (tap == 2 && wpos == 55);
#pragma unroll
        for (int ks8 = 0; ks8 < 8; ++ks8) {
            bf16x8 b = *(const bf16x8*)(brow + ks8 * 16);
            if (kill) {
#pragma unroll
                for (int t = 0; t < 8; ++t) b[t] = 0;
            }
            const bf16x8 a = *(const bf16x8*)(af + (tap * 8 + ks8) * 512 + lane * 8);
            acc = __builtin_amdgcn_mfma_f32_32x32x16_bf16(a, b, acc, 0, 0, 0);
        }
    }

    // ---- store with roll: s -> (s+56) mod 3136 ; C/D: col=lane&31, row=(r&3)+8*(r>>2)+4*half
    if (cloc < ST && col < SP) {
        int sst = col + 56;
        if (sst >= SP) sst -= SP;
        float* op = out + (size_t)n * (OUTC * SP) + sst;
#pragma unroll
        for (int r = 0; r < 16; ++r) {
            int o = (r & 3) + 8 * (r >> 2) + 4 * half;
            op[o * SP] = acc[r];
        }
    }
}

extern "C" void kernel_launch(void* const* d_in, const int* in_sizes, int n_in,
                              void* d_out, int out_size, void* d_ws, size_t ws_size,
                              hipStream_t stream) {
    const float* x = (const float*)d_in[0];
    const float* w = (const float*)d_in[1];
    float* out = (float*)d_out;
    unsigned short* af = (unsigned short*)d_ws;        // 24*512 bf16 = 24 KB

    prep_w<<<dim3((OUTC * 384 + 255) / 256), dim3(256), 0, stream>>>(w, af);

    dim3 grid(NT, NB);                                  // 25 x 128
    conv_mfma<<<grid, dim3(THREADS), 0, stream>>>(x, af, out);
}